// Round 2
// baseline (1132.312 us; speedup 1.0000x reference)
//
#include <hip/hip_runtime.h>
#include <hip/hip_bf16.h>

#define BATCH 32
#define NN 1024
#define MM 1024
#define KK 64
#define DD 2052                         // padded diag count (N+M-1=2047, +prefetch pad)
#define SCALE 14.4269504088896f         // 1/(gamma*ln2), gamma = 0.1
#define INV_SCALE 0.0693147180559945f   // gamma*ln2
#define BIGU 1.44269504e11f             // 1e10 * SCALE

typedef _Float16 h4 __attribute__((ext_vector_type(4)));
typedef float f4 __attribute__((ext_vector_type(4)));

// ---------------------------------------------------------------------------
// Kernel 1: pairwise sq-Euclidean distances, pre-scaled by 1/(gamma*ln2),
// stored f16. 64x64 tile / 256 threads / 4x4 per thread.
// DIAG=1: store D[b][i+j][i] (anti-diagonal-major, coalesced for the DP).
// DIAG=0: store D[b][i][j]   (row-major fallback, 64 MiB).
// ---------------------------------------------------------------------------
template <int DIAG>
__global__ __launch_bounds__(256) void dist_kernel(
    const float* __restrict__ x, const float* __restrict__ y,
    _Float16* __restrict__ D) {
  const int b  = blockIdx.z;
  const int ti = blockIdx.y;
  const int tj = blockIdx.x;
  const int t  = threadIdx.x;

  __shared__ float xs[64][68];
  __shared__ float ys[64][68];

  {
    const int lr = t >> 4;
    const int lc = (t & 15) * 4;
    const float* xp = x + (size_t)(b * NN + ti * 64) * KK;
    const float* yp = y + (size_t)(b * MM + tj * 64) * KK;
#pragma unroll
    for (int r = 0; r < 4; ++r) {
      const int row = lr + r * 16;
      f4 xv = *(const f4*)(xp + (size_t)row * KK + lc);
      f4 yv = *(const f4*)(yp + (size_t)row * KK + lc);
      xs[row][lc + 0] = xv[0]; xs[row][lc + 1] = xv[1];
      xs[row][lc + 2] = xv[2]; xs[row][lc + 3] = xv[3];
      ys[row][lc + 0] = yv[0]; ys[row][lc + 1] = yv[1];
      ys[row][lc + 2] = yv[2]; ys[row][lc + 3] = yv[3];
    }
  }
  __syncthreads();

  const int tx = (t & 15) * 4;
  const int ty = (t >> 4) * 4;

  float acc[4][4];
  float x2[4], y2[4];
#pragma unroll
  for (int a = 0; a < 4; ++a) {
    x2[a] = 0.f; y2[a] = 0.f;
#pragma unroll
    for (int c = 0; c < 4; ++c) acc[a][c] = 0.f;
  }

#pragma unroll 4
  for (int k = 0; k < KK; k += 4) {
    f4 xa[4], yb[4];
#pragma unroll
    for (int a = 0; a < 4; ++a) xa[a] = *(const f4*)&xs[ty + a][k];
#pragma unroll
    for (int c = 0; c < 4; ++c) yb[c] = *(const f4*)&ys[tx + c][k];
#pragma unroll
    for (int a = 0; a < 4; ++a) {
      x2[a] += xa[a][0] * xa[a][0] + xa[a][1] * xa[a][1] +
               xa[a][2] * xa[a][2] + xa[a][3] * xa[a][3];
      y2[a] += yb[a][0] * yb[a][0] + yb[a][1] * yb[a][1] +
               yb[a][2] * yb[a][2] + yb[a][3] * yb[a][3];
    }
#pragma unroll
    for (int a = 0; a < 4; ++a)
#pragma unroll
      for (int c = 0; c < 4; ++c)
        acc[a][c] += xa[a][0] * yb[c][0] + xa[a][1] * yb[c][1] +
                     xa[a][2] * yb[c][2] + xa[a][3] * yb[c][3];
  }

  if constexpr (DIAG) {
    _Float16* Db = D + (size_t)b * DD * NN;
    const int gi0 = ti * 64 + ty;
    const int gj0 = tj * 64 + tx;
#pragma unroll
    for (int a = 0; a < 4; ++a)
#pragma unroll
      for (int c = 0; c < 4; ++c) {
        const int gi = gi0 + a, gj = gj0 + c;
        Db[(size_t)(gi + gj) * NN + gi] =
            (_Float16)((x2[a] + y2[c] - 2.0f * acc[a][c]) * SCALE);
      }
  } else {
    _Float16* Dp = D + (size_t)b * NN * MM + (size_t)(ti * 64 + ty) * MM +
                   (tj * 64 + tx);
#pragma unroll
    for (int a = 0; a < 4; ++a) {
      h4 v;
#pragma unroll
      for (int c = 0; c < 4; ++c)
        v[c] = (_Float16)((x2[a] + y2[c] - 2.0f * acc[a][c]) * SCALE);
      *(h4*)(Dp + (size_t)a * MM) = v;
    }
  }
}

// ---------------------------------------------------------------------------
// Kernel 2 (diag layout): wavefront DP, 1 block/batch, 256 threads, 4 rows
// per thread. Scaled log2 domain: u = R/(gamma*ln2);
//   softmin_u(a,b,c) = m - log2(2^(m-a)+2^(m-b)+2^(m-c)), m = min3.
// One LDS float exchanged per diagonal (nl2 is last iteration's nl1).
// D loads are coalesced h4 reads, prefetched 2 diagonals ahead.
// ---------------------------------------------------------------------------
__global__ __launch_bounds__(256) void dtw_diag_kernel(
    const _Float16* __restrict__ Dd, float* __restrict__ out) {
  const int b  = blockIdx.x;
  const int t  = threadIdx.x;
  const int i0 = t * 4;
  const _Float16* Db = Dd + (size_t)b * DD * NN;

  __shared__ float lx[2][256];

  float r1[4], r2[4];
#pragma unroll
  for (int k = 0; k < 4; ++k) { r1[k] = BIGU; r2[k] = BIGU; }
  if (t == 0) r1[0] = (float)Db[0];

  h4 dv  = *(const h4*)(Db + (size_t)1 * NN + i0);
  h4 dvn = *(const h4*)(Db + (size_t)2 * NN + i0);

  float nl1_prev = BIGU;

  for (int d = 1; d <= NN + MM - 2; ++d) {
    const int pp = d & 1;
    lx[pp][t] = r1[3];
    __syncthreads();
    const float nl1 = (t > 0) ? lx[pp][t - 1] : BIGU;  // R[i0-1] @ diag d-1
    const float nl2 = nl1_prev;                         // R[i0-1] @ diag d-2

    float rn[4];
#pragma unroll
    for (int k = 0; k < 4; ++k) {
      const int j = d - (i0 + k);
      const float a  = k ? r2[k - 1] : nl2;  // R[i-1, j-1]
      const float bb = k ? r1[k - 1] : nl1;  // R[i-1, j]
      const float c  = r1[k];                // R[i,   j-1]
      const float m  = fminf(fminf(a, bb), c);
      const float s  = exp2f(m - a) + exp2f(m - bb) + exp2f(m - c);
      const float sm = m - log2f(s);
      rn[k] = (j >= 0 && j < MM) ? (float)dv[k] + sm : BIGU;
    }

    nl1_prev = nl1;
#pragma unroll
    for (int k = 0; k < 4; ++k) { r2[k] = r1[k]; r1[k] = rn[k]; }
    dv  = dvn;
    dvn = *(const h4*)(Db + (size_t)(d + 2) * NN + i0);
  }

  if (t == 255) out[b] = r1[3] * INV_SCALE;
}

// ---------------------------------------------------------------------------
// Kernel 2 (row-major fallback): same DP, clamped scalar f16 loads.
// ---------------------------------------------------------------------------
__global__ __launch_bounds__(256) void dtw_row_kernel(
    const _Float16* __restrict__ D, float* __restrict__ out) {
  const int b  = blockIdx.x;
  const int t  = threadIdx.x;
  const int i0 = t * 4;
  const _Float16* Dr = D + (size_t)(b * NN + i0) * MM;

  __shared__ float lx[2][256];

  float r1[4], r2[4];
#pragma unroll
  for (int k = 0; k < 4; ++k) { r1[k] = BIGU; r2[k] = BIGU; }
  if (t == 0) r1[0] = (float)Dr[0];

  float dv[4], dvn[4];
#pragma unroll
  for (int k = 0; k < 4; ++k) {
    int j1 = 1 - (i0 + k);
    int jc1 = j1 < 0 ? 0 : (j1 > MM - 1 ? MM - 1 : j1);
    dv[k] = (float)Dr[(size_t)k * MM + jc1];
    int j2 = 2 - (i0 + k);
    int jc2 = j2 < 0 ? 0 : (j2 > MM - 1 ? MM - 1 : j2);
    dvn[k] = (float)Dr[(size_t)k * MM + jc2];
  }

  float nl1_prev = BIGU;

  for (int d = 1; d <= NN + MM - 2; ++d) {
    const int pp = d & 1;
    lx[pp][t] = r1[3];
    __syncthreads();
    const float nl1 = (t > 0) ? lx[pp][t - 1] : BIGU;
    const float nl2 = nl1_prev;

    float rn[4];
#pragma unroll
    for (int k = 0; k < 4; ++k) {
      const int j = d - (i0 + k);
      const float a  = k ? r2[k - 1] : nl2;
      const float bb = k ? r1[k - 1] : nl1;
      const float c  = r1[k];
      const float m  = fminf(fminf(a, bb), c);
      const float s  = exp2f(m - a) + exp2f(m - bb) + exp2f(m - c);
      const float sm = m - log2f(s);
      rn[k] = (j >= 0 && j < MM) ? dv[k] + sm : BIGU;
    }

    nl1_prev = nl1;
#pragma unroll
    for (int k = 0; k < 4; ++k) { r2[k] = r1[k]; r1[k] = rn[k]; dv[k] = dvn[k]; }

    const int dn = d + 2;
#pragma unroll
    for (int k = 0; k < 4; ++k) {
      int j = dn - (i0 + k);
      int jc = j < 0 ? 0 : (j > MM - 1 ? MM - 1 : j);
      dvn[k] = (float)Dr[(size_t)k * MM + jc];
    }
  }

  if (t == 255) out[b] = r1[3] * INV_SCALE;
}

// ---------------------------------------------------------------------------
extern "C" void kernel_launch(void* const* d_in, const int* in_sizes, int n_in,
                              void* d_out, int out_size, void* d_ws,
                              size_t ws_size, hipStream_t stream) {
  const float* x = (const float*)d_in[0];
  const float* y = (const float*)d_in[1];
  float* out = (float*)d_out;

  const size_t need_diag = (size_t)BATCH * DD * NN * sizeof(_Float16);  // ~134.5 MiB
  const size_t need_row  = (size_t)BATCH * NN * MM * sizeof(_Float16);  //   64  MiB
  dim3 g1(MM / 64, NN / 64, BATCH);

  if (ws_size >= need_diag) {
    _Float16* Dd = (_Float16*)d_ws;
    dist_kernel<1><<<g1, 256, 0, stream>>>(x, y, Dd);
    dtw_diag_kernel<<<BATCH, 256, 0, stream>>>(Dd, out);
  } else if (ws_size >= need_row) {
    _Float16* D = (_Float16*)d_ws;
    dist_kernel<0><<<g1, 256, 0, stream>>>(x, y, D);
    dtw_row_kernel<<<BATCH, 256, 0, stream>>>(D, out);
  }
  // else: workspace too small — fail visibly (output stays zero)
}

// Round 5
// 1125.484 us; speedup vs baseline: 1.0061x; 1.0061x over previous
//
#include <hip/hip_runtime.h>
#include <hip/hip_bf16.h>

#define BATCH 32
#define NN 1024
#define MM 1024
#define KK 64
#define DD 2052                         // padded diag rows (N+M-1=2047, + prefetch pad)
#define SCALE 14.4269504088896f         // 1/(gamma*ln2), gamma = 0.1
#define INV_SCALE 0.0693147180559945f   // gamma*ln2
#define BIGU 1.44269504e11f             // 1e10 * SCALE

typedef _Float16 h4 __attribute__((ext_vector_type(4)));
typedef float f4 __attribute__((ext_vector_type(4)));

// ---------------------------------------------------------------------------
// Kernel 1: pairwise sq-Euclidean distances, pre-scaled by 1/(gamma*ln2),
// stored f16. 64x64 tile / 256 threads / 4x4 per thread.
// DIAG=1: D[b][i+j][i] (anti-diagonal-major). Epilogue transposes the 4x4
//         register tiles through LDS so global stores are lane-consecutive
//         (128B contiguous runs per anti-diagonal) instead of 2B scatter.
// DIAG=0: row-major fallback (64 MiB).
// ---------------------------------------------------------------------------
template <int DIAG>
__global__ __launch_bounds__(256) void dist_kernel(
    const float* __restrict__ x, const float* __restrict__ y,
    _Float16* __restrict__ D) {
  const int b  = blockIdx.z;
  const int ti = blockIdx.y;
  const int tj = blockIdx.x;
  const int t  = threadIdx.x;

  __shared__ float xs[64][68];
  __shared__ float ys[64][68];

  {
    const int lr = t >> 4;
    const int lc = (t & 15) * 4;
    const float* xp = x + (size_t)(b * NN + ti * 64) * KK;
    const float* yp = y + (size_t)(b * MM + tj * 64) * KK;
#pragma unroll
    for (int r = 0; r < 4; ++r) {
      const int row = lr + r * 16;
      f4 xv = *(const f4*)(xp + (size_t)row * KK + lc);
      f4 yv = *(const f4*)(yp + (size_t)row * KK + lc);
      xs[row][lc + 0] = xv[0]; xs[row][lc + 1] = xv[1];
      xs[row][lc + 2] = xv[2]; xs[row][lc + 3] = xv[3];
      ys[row][lc + 0] = yv[0]; ys[row][lc + 1] = yv[1];
      ys[row][lc + 2] = yv[2]; ys[row][lc + 3] = yv[3];
    }
  }
  __syncthreads();

  const int tx = (t & 15) * 4;   // local j offset
  const int ty = (t >> 4) * 4;   // local i offset

  float acc[4][4];
  float x2[4], y2[4];
#pragma unroll
  for (int a = 0; a < 4; ++a) {
    x2[a] = 0.f; y2[a] = 0.f;
#pragma unroll
    for (int c = 0; c < 4; ++c) acc[a][c] = 0.f;
  }

#pragma unroll 4
  for (int k = 0; k < KK; k += 4) {
    f4 xa[4], yb[4];
#pragma unroll
    for (int a = 0; a < 4; ++a) xa[a] = *(const f4*)&xs[ty + a][k];
#pragma unroll
    for (int c = 0; c < 4; ++c) yb[c] = *(const f4*)&ys[tx + c][k];
#pragma unroll
    for (int a = 0; a < 4; ++a) {
      x2[a] += xa[a][0] * xa[a][0] + xa[a][1] * xa[a][1] +
               xa[a][2] * xa[a][2] + xa[a][3] * xa[a][3];
      y2[a] += yb[a][0] * yb[a][0] + yb[a][1] * yb[a][1] +
               yb[a][2] * yb[a][2] + yb[a][3] * yb[a][3];
    }
#pragma unroll
    for (int a = 0; a < 4; ++a)
#pragma unroll
      for (int c = 0; c < 4; ++c)
        acc[a][c] += xa[a][0] * yb[c][0] + xa[a][1] * yb[c][1] +
                     xa[a][2] * yb[c][2] + xa[a][3] * yb[c][3];
  }

  if constexpr (DIAG) {
    // Local diag transpose: dbuf[ld][li], ld = li+lj in [0,126], li in [0,63].
    __shared__ _Float16 dbuf[127][66];
#pragma unroll
    for (int a = 0; a < 4; ++a)
#pragma unroll
      for (int c = 0; c < 4; ++c) {
        const int li = ty + a, lj = tx + c;
        dbuf[li + lj][li] =
            (_Float16)((x2[a] + y2[c] - 2.0f * acc[a][c]) * SCALE);
      }
    __syncthreads();

    _Float16* Db = D + (size_t)b * DD * NN;
    const int wave = t >> 6, lane = t & 63;
    const int d0 = ti * 64 + tj * 64;   // global diag of local ld=0
    const int c0 = ti * 64;             // global i of local li=0
    for (int ld = wave; ld < 127; ld += 4) {
      const int lo = ld > 63 ? ld - 63 : 0;
      const int hi = ld < 63 ? ld : 63;
      const int li = lo + lane;
      if (li <= hi)
        Db[(size_t)(d0 + ld) * NN + c0 + li] = dbuf[ld][li];
    }
  } else {
    _Float16* Dp = D + (size_t)b * NN * MM + (size_t)(ti * 64 + ty) * MM +
                   (tj * 64 + tx);
#pragma unroll
    for (int a = 0; a < 4; ++a) {
      h4 v;
#pragma unroll
      for (int c = 0; c < 4; ++c)
        v[c] = (_Float16)((x2[a] + y2[c] - 2.0f * acc[a][c]) * SCALE);
      *(h4*)(Dp + (size_t)a * MM) = v;
    }
  }
}

// ---------------------------------------------------------------------------
// Kernel 2 (diag layout): wavefront DP, 1 block/batch, 256 threads, 4 rows
// per thread, scaled log2 domain:
//   softmin_u(a,b,c) = m - log2(2^(m-a)+2^(m-b)+2^(m-c)), m = min3.
// D prefetched via a 4-deep register ring with STATIC indices (loop unrolled
// x4): ring[r] is consumed, then reloaded for diag d+4 — no register copy,
// so the compiler emits counted s_waitcnt vmcnt(3) and loads stay in flight
// for ~4 iterations (covers L3/HBM latency off the serial critical path).
// One LDS float exchanged per diagonal (nl2 is last iteration's nl1).
// ---------------------------------------------------------------------------
__global__ __launch_bounds__(256) void dtw_diag_kernel(
    const _Float16* __restrict__ Dd, float* __restrict__ out) {
  const int b  = blockIdx.x;
  const int t  = threadIdx.x;
  const int i0 = t * 4;
  const _Float16* Db = Dd + (size_t)b * DD * NN;

  __shared__ float lx[2][256];

  float r1[4], r2[4];
#pragma unroll
  for (int k = 0; k < 4; ++k) { r1[k] = BIGU; r2[k] = BIGU; }
  if (t == 0) r1[0] = (float)Db[0];

  h4 ring[4];
#pragma unroll
  for (int r = 0; r < 4; ++r)
    ring[r] = *(const h4*)(Db + (size_t)(1 + r) * NN + i0);  // diags 1..4

  float nl1_prev = BIGU;

  // Main loop: 511 blocks of 4 diagonals, d = 1..2044.
  for (int d0 = 1; d0 <= NN + MM - 6; d0 += 4) {
#pragma unroll
    for (int r = 0; r < 4; ++r) {
      const int d = d0 + r;
      lx[d & 1][t] = r1[3];
      __syncthreads();
      const float nl1 = (t > 0) ? lx[d & 1][t - 1] : BIGU;  // R[i0-1] @ d-1
      const float nl2 = nl1_prev;                            // R[i0-1] @ d-2

      float rn[4];
#pragma unroll
      for (int k = 0; k < 4; ++k) {
        const float a  = k ? r2[k - 1] : nl2;  // R[i-1, j-1]
        const float bb = k ? r1[k - 1] : nl1;  // R[i-1, j]
        const float c  = r1[k];                // R[i,   j-1]
        const float m  = fminf(fminf(a, bb), c);
        const float s  = exp2f(m - a) + exp2f(m - bb) + exp2f(m - c);
        const float sm = m - log2f(s);
        const unsigned ju = (unsigned)(d - (i0 + k));        // valid iff < MM
        rn[k] = (ju < MM) ? (float)ring[r][k] + sm : BIGU;
      }

      nl1_prev = nl1;
#pragma unroll
      for (int k = 0; k < 4; ++k) { r2[k] = r1[k]; r1[k] = rn[k]; }

      // Prefetch diag d+4 into the slot just consumed (max row 2048 < DD).
      ring[r] = *(const h4*)(Db + (size_t)(d + 4) * NN + i0);
    }
  }

  // Peel d = 2045, 2046 (ring[0..1] hold diags 2045, 2046; no more loads).
#pragma unroll
  for (int r = 0; r < 2; ++r) {
    const int d = NN + MM - 3 + r;  // 2045 + r
    lx[d & 1][t] = r1[3];
    __syncthreads();
    const float nl1 = (t > 0) ? lx[d & 1][t - 1] : BIGU;
    const float nl2 = nl1_prev;

    float rn[4];
#pragma unroll
    for (int k = 0; k < 4; ++k) {
      const float a  = k ? r2[k - 1] : nl2;
      const float bb = k ? r1[k - 1] : nl1;
      const float c  = r1[k];
      const float m  = fminf(fminf(a, bb), c);
      const float s  = exp2f(m - a) + exp2f(m - bb) + exp2f(m - c);
      const float sm = m - log2f(s);
      const unsigned ju = (unsigned)(d - (i0 + k));
      rn[k] = (ju < MM) ? (float)ring[r][k] + sm : BIGU;
    }

    nl1_prev = nl1;
#pragma unroll
    for (int k = 0; k < 4; ++k) { r2[k] = r1[k]; r1[k] = rn[k]; }
  }

  if (t == 255) out[b] = r1[3] * INV_SCALE;
}

// ---------------------------------------------------------------------------
// Kernel 2 (row-major fallback): unchanged from the verified round-2 version.
// ---------------------------------------------------------------------------
__global__ __launch_bounds__(256) void dtw_row_kernel(
    const _Float16* __restrict__ D, float* __restrict__ out) {
  const int b  = blockIdx.x;
  const int t  = threadIdx.x;
  const int i0 = t * 4;
  const _Float16* Dr = D + (size_t)(b * NN + i0) * MM;

  __shared__ float lx[2][256];

  float r1[4], r2[4];
#pragma unroll
  for (int k = 0; k < 4; ++k) { r1[k] = BIGU; r2[k] = BIGU; }
  if (t == 0) r1[0] = (float)Dr[0];

  float dv[4], dvn[4];
#pragma unroll
  for (int k = 0; k < 4; ++k) {
    int j1 = 1 - (i0 + k);
    int jc1 = j1 < 0 ? 0 : (j1 > MM - 1 ? MM - 1 : j1);
    dv[k] = (float)Dr[(size_t)k * MM + jc1];
    int j2 = 2 - (i0 + k);
    int jc2 = j2 < 0 ? 0 : (j2 > MM - 1 ? MM - 1 : j2);
    dvn[k] = (float)Dr[(size_t)k * MM + jc2];
  }

  float nl1_prev = BIGU;

  for (int d = 1; d <= NN + MM - 2; ++d) {
    const int pp = d & 1;
    lx[pp][t] = r1[3];
    __syncthreads();
    const float nl1 = (t > 0) ? lx[pp][t - 1] : BIGU;
    const float nl2 = nl1_prev;

    float rn[4];
#pragma unroll
    for (int k = 0; k < 4; ++k) {
      const int j = d - (i0 + k);
      const float a  = k ? r2[k - 1] : nl2;
      const float bb = k ? r1[k - 1] : nl1;
      const float c  = r1[k];
      const float m  = fminf(fminf(a, bb), c);
      const float s  = exp2f(m - a) + exp2f(m - bb) + exp2f(m - c);
      const float sm = m - log2f(s);
      rn[k] = (j >= 0 && j < MM) ? dv[k] + sm : BIGU;
    }

    nl1_prev = nl1;
#pragma unroll
    for (int k = 0; k < 4; ++k) { r2[k] = r1[k]; r1[k] = rn[k]; dv[k] = dvn[k]; }

    const int dn = d + 2;
#pragma unroll
    for (int k = 0; k < 4; ++k) {
      int j = dn - (i0 + k);
      int jc = j < 0 ? 0 : (j > MM - 1 ? MM - 1 : j);
      dvn[k] = (float)Dr[(size_t)k * MM + jc];
    }
  }

  if (t == 255) out[b] = r1[3] * INV_SCALE;
}

// ---------------------------------------------------------------------------
extern "C" void kernel_launch(void* const* d_in, const int* in_sizes, int n_in,
                              void* d_out, int out_size, void* d_ws,
                              size_t ws_size, hipStream_t stream) {
  const float* x = (const float*)d_in[0];
  const float* y = (const float*)d_in[1];
  float* out = (float*)d_out;

  const size_t need_diag = (size_t)BATCH * DD * NN * sizeof(_Float16);  // ~134.5 MiB
  const size_t need_row  = (size_t)BATCH * NN * MM * sizeof(_Float16);  //   64  MiB
  dim3 g1(MM / 64, NN / 64, BATCH);

  if (ws_size >= need_diag) {
    _Float16* Dd = (_Float16*)d_ws;
    dist_kernel<1><<<g1, 256, 0, stream>>>(x, y, Dd);
    dtw_diag_kernel<<<BATCH, 256, 0, stream>>>(Dd, out);
  } else if (ws_size >= need_row) {
    _Float16* D = (_Float16*)d_ws;
    dist_kernel<0><<<g1, 256, 0, stream>>>(x, y, D);
    dtw_row_kernel<<<BATCH, 256, 0, stream>>>(D, out);
  }
  // else: workspace too small — fail visibly (output stays zero)
}

// Round 7
// 1099.320 us; speedup vs baseline: 1.0300x; 1.0238x over previous
//
#include <hip/hip_runtime.h>
#include <hip/hip_bf16.h>

#define BATCH 32
#define NN 1024
#define MM 1024
#define KK 64
#define DD 2052                         // padded diag rows (N+M-1=2047, + prefetch pad)
#define SCALE 14.4269504088896f         // 1/(gamma*ln2), gamma = 0.1
#define INV_SCALE 0.0693147180559945f   // gamma*ln2
#define BIGU 1.44269504e11f             // 1e10 * SCALE

typedef _Float16 h4 __attribute__((ext_vector_type(4)));
typedef float f4 __attribute__((ext_vector_type(4)));

// Raw barrier WITHOUT the __syncthreads() vmcnt(0) drain: LDS visibility only.
// Keeps the D-prefetch ring's global loads in flight across diagonals (T3/T4
// pattern); the compiler still emits counted vmcnt(N) before each ring use.
#define LDS_BARRIER()                                         \
  do {                                                        \
    asm volatile("s_waitcnt lgkmcnt(0)" ::: "memory");        \
    __builtin_amdgcn_s_barrier();                             \
  } while (0)

// ---------------------------------------------------------------------------
// Kernel 1: pairwise sq-Euclidean distances, pre-scaled by 1/(gamma*ln2),
// stored f16. 64x64 tile / 256 threads / 4x4 per thread.
// DIAG=1: D[b][i+j][i] (anti-diagonal-major). Epilogue transposes the 4x4
//         register tiles through LDS so global stores are lane-consecutive.
// DIAG=0: row-major fallback (64 MiB).
// ---------------------------------------------------------------------------
template <int DIAG>
__global__ __launch_bounds__(256) void dist_kernel(
    const float* __restrict__ x, const float* __restrict__ y,
    _Float16* __restrict__ D) {
  const int b  = blockIdx.z;
  const int ti = blockIdx.y;
  const int tj = blockIdx.x;
  const int t  = threadIdx.x;

  __shared__ float xs[64][68];
  __shared__ float ys[64][68];

  {
    const int lr = t >> 4;
    const int lc = (t & 15) * 4;
    const float* xp = x + (size_t)(b * NN + ti * 64) * KK;
    const float* yp = y + (size_t)(b * MM + tj * 64) * KK;
#pragma unroll
    for (int r = 0; r < 4; ++r) {
      const int row = lr + r * 16;
      f4 xv = *(const f4*)(xp + (size_t)row * KK + lc);
      f4 yv = *(const f4*)(yp + (size_t)row * KK + lc);
      xs[row][lc + 0] = xv[0]; xs[row][lc + 1] = xv[1];
      xs[row][lc + 2] = xv[2]; xs[row][lc + 3] = xv[3];
      ys[row][lc + 0] = yv[0]; ys[row][lc + 1] = yv[1];
      ys[row][lc + 2] = yv[2]; ys[row][lc + 3] = yv[3];
    }
  }
  __syncthreads();

  const int tx = (t & 15) * 4;   // local j offset
  const int ty = (t >> 4) * 4;   // local i offset

  float acc[4][4];
  float x2[4], y2[4];
#pragma unroll
  for (int a = 0; a < 4; ++a) {
    x2[a] = 0.f; y2[a] = 0.f;
#pragma unroll
    for (int c = 0; c < 4; ++c) acc[a][c] = 0.f;
  }

#pragma unroll 4
  for (int k = 0; k < KK; k += 4) {
    f4 xa[4], yb[4];
#pragma unroll
    for (int a = 0; a < 4; ++a) xa[a] = *(const f4*)&xs[ty + a][k];
#pragma unroll
    for (int c = 0; c < 4; ++c) yb[c] = *(const f4*)&ys[tx + c][k];
#pragma unroll
    for (int a = 0; a < 4; ++a) {
      x2[a] += xa[a][0] * xa[a][0] + xa[a][1] * xa[a][1] +
               xa[a][2] * xa[a][2] + xa[a][3] * xa[a][3];
      y2[a] += yb[a][0] * yb[a][0] + yb[a][1] * yb[a][1] +
               yb[a][2] * yb[a][2] + yb[a][3] * yb[a][3];
    }
#pragma unroll
    for (int a = 0; a < 4; ++a)
#pragma unroll
      for (int c = 0; c < 4; ++c)
        acc[a][c] += xa[a][0] * yb[c][0] + xa[a][1] * yb[c][1] +
                     xa[a][2] * yb[c][2] + xa[a][3] * yb[c][3];
  }

  if constexpr (DIAG) {
    // Local diag transpose: dbuf[ld][li], ld = li+lj in [0,126], li in [0,63].
    __shared__ _Float16 dbuf[127][66];
#pragma unroll
    for (int a = 0; a < 4; ++a)
#pragma unroll
      for (int c = 0; c < 4; ++c) {
        const int li = ty + a, lj = tx + c;
        dbuf[li + lj][li] =
            (_Float16)((x2[a] + y2[c] - 2.0f * acc[a][c]) * SCALE);
      }
    __syncthreads();

    _Float16* Db = D + (size_t)b * DD * NN;
    const int wave = t >> 6, lane = t & 63;
    const int d0 = ti * 64 + tj * 64;   // global diag of local ld=0
    const int c0 = ti * 64;             // global i of local li=0
    for (int ld = wave; ld < 127; ld += 4) {
      const int lo = ld > 63 ? ld - 63 : 0;
      const int hi = ld < 63 ? ld : 63;
      const int li = lo + lane;
      if (li <= hi)
        Db[(size_t)(d0 + ld) * NN + c0 + li] = dbuf[ld][li];
    }
  } else {
    _Float16* Dp = D + (size_t)b * NN * MM + (size_t)(ti * 64 + ty) * MM +
                   (tj * 64 + tx);
#pragma unroll
    for (int a = 0; a < 4; ++a) {
      h4 v;
#pragma unroll
      for (int c = 0; c < 4; ++c)
        v[c] = (_Float16)((x2[a] + y2[c] - 2.0f * acc[a][c]) * SCALE);
      *(h4*)(Dp + (size_t)a * MM) = v;
    }
  }
}

// ---------------------------------------------------------------------------
// Kernel 2 (diag layout): wavefront DP, 1 block/batch, 256 threads, 4 rows
// per thread, scaled log2 domain:
//   softmin_u(a,b,c) = m - log2(2^(m-a)+2^(m-b)+2^(m-c)), m = min3.
// D prefetched via an 8-deep register ring (static indices, loop unrolled x8).
// Barriers are raw s_barrier + lgkmcnt(0) ONLY — no vmcnt drain, so the ring
// loads stay in flight across up to 8 diagonals (covers ~900cy HBM latency).
// One LDS float exchanged per diagonal (nl2 is last iteration's nl1).
// ---------------------------------------------------------------------------
__global__ __launch_bounds__(256) void dtw_diag_kernel(
    const _Float16* __restrict__ Dd, float* __restrict__ out) {
  const int b  = blockIdx.x;
  const int t  = threadIdx.x;
  const int i0 = t * 4;
  const _Float16* Db = Dd + (size_t)b * DD * NN;

  __shared__ float lx[2][256];

  float r1[4], r2[4];
#pragma unroll
  for (int k = 0; k < 4; ++k) { r1[k] = BIGU; r2[k] = BIGU; }
  if (t == 0) r1[0] = (float)Db[0];

  h4 ring[8];
#pragma unroll
  for (int r = 0; r < 8; ++r)
    ring[r] = *(const h4*)(Db + (size_t)(1 + r) * NN + i0);  // diags 1..8

  float nl1_prev = BIGU;

  // Main loop: 255 blocks of 8 diagonals, d = 1..2040.
  for (int d0 = 1; d0 <= NN + MM - 15; d0 += 8) {
#pragma unroll
    for (int r = 0; r < 8; ++r) {
      const int d = d0 + r;
      lx[d & 1][t] = r1[3];
      LDS_BARRIER();
      const float nl1 = (t > 0) ? lx[d & 1][t - 1] : BIGU;  // R[i0-1] @ d-1
      const float nl2 = nl1_prev;                            // R[i0-1] @ d-2

      float rn[4];
#pragma unroll
      for (int k = 0; k < 4; ++k) {
        const float a  = k ? r2[k - 1] : nl2;  // R[i-1, j-1]
        const float bb = k ? r1[k - 1] : nl1;  // R[i-1, j]
        const float c  = r1[k];                // R[i,   j-1]
        const float m  = fminf(fminf(a, bb), c);
        const float s  = exp2f(m - a) + exp2f(m - bb) + exp2f(m - c);
        const float sm = m - log2f(s);
        const unsigned ju = (unsigned)(d - (i0 + k));        // valid iff < MM
        rn[k] = (ju < MM) ? (float)ring[r][k] + sm : BIGU;
      }

      nl1_prev = nl1;
#pragma unroll
      for (int k = 0; k < 4; ++k) { r2[k] = r1[k]; r1[k] = rn[k]; }

      // Prefetch diag d+8 into the slot just consumed (max row 2048 < DD).
      ring[r] = *(const h4*)(Db + (size_t)(d + 8) * NN + i0);
    }
  }

  // Peel d = 2041..2046 (ring[0..5] hold diags 2041..2046; no more loads).
#pragma unroll
  for (int r = 0; r < 6; ++r) {
    const int d = NN + MM - 7 + r;  // 2041 + r
    lx[d & 1][t] = r1[3];
    LDS_BARRIER();
    const float nl1 = (t > 0) ? lx[d & 1][t - 1] : BIGU;
    const float nl2 = nl1_prev;

    float rn[4];
#pragma unroll
    for (int k = 0; k < 4; ++k) {
      const float a  = k ? r2[k - 1] : nl2;
      const float bb = k ? r1[k - 1] : nl1;
      const float c  = r1[k];
      const float m  = fminf(fminf(a, bb), c);
      const float s  = exp2f(m - a) + exp2f(m - bb) + exp2f(m - c);
      const float sm = m - log2f(s);
      const unsigned ju = (unsigned)(d - (i0 + k));
      rn[k] = (ju < MM) ? (float)ring[r][k] + sm : BIGU;
    }

    nl1_prev = nl1;
#pragma unroll
    for (int k = 0; k < 4; ++k) { r2[k] = r1[k]; r1[k] = rn[k]; }
  }

  if (t == 255) out[b] = r1[3] * INV_SCALE;
}

// ---------------------------------------------------------------------------
// Kernel 2 (row-major fallback): unchanged verified version.
// ---------------------------------------------------------------------------
__global__ __launch_bounds__(256) void dtw_row_kernel(
    const _Float16* __restrict__ D, float* __restrict__ out) {
  const int b  = blockIdx.x;
  const int t  = threadIdx.x;
  const int i0 = t * 4;
  const _Float16* Dr = D + (size_t)(b * NN + i0) * MM;

  __shared__ float lx[2][256];

  float r1[4], r2[4];
#pragma unroll
  for (int k = 0; k < 4; ++k) { r1[k] = BIGU; r2[k] = BIGU; }
  if (t == 0) r1[0] = (float)Dr[0];

  float dv[4], dvn[4];
#pragma unroll
  for (int k = 0; k < 4; ++k) {
    int j1 = 1 - (i0 + k);
    int jc1 = j1 < 0 ? 0 : (j1 > MM - 1 ? MM - 1 : j1);
    dv[k] = (float)Dr[(size_t)k * MM + jc1];
    int j2 = 2 - (i0 + k);
    int jc2 = j2 < 0 ? 0 : (j2 > MM - 1 ? MM - 1 : j2);
    dvn[k] = (float)Dr[(size_t)k * MM + jc2];
  }

  float nl1_prev = BIGU;

  for (int d = 1; d <= NN + MM - 2; ++d) {
    const int pp = d & 1;
    lx[pp][t] = r1[3];
    __syncthreads();
    const float nl1 = (t > 0) ? lx[pp][t - 1] : BIGU;
    const float nl2 = nl1_prev;

    float rn[4];
#pragma unroll
    for (int k = 0; k < 4; ++k) {
      const int j = d - (i0 + k);
      const float a  = k ? r2[k - 1] : nl2;
      const float bb = k ? r1[k - 1] : nl1;
      const float c  = r1[k];
      const float m  = fminf(fminf(a, bb), c);
      const float s  = exp2f(m - a) + exp2f(m - bb) + exp2f(m - c);
      const float sm = m - log2f(s);
      rn[k] = (j >= 0 && j < MM) ? dv[k] + sm : BIGU;
    }

    nl1_prev = nl1;
#pragma unroll
    for (int k = 0; k < 4; ++k) { r2[k] = r1[k]; r1[k] = rn[k]; dv[k] = dvn[k]; }

    const int dn = d + 2;
#pragma unroll
    for (int k = 0; k < 4; ++k) {
      int j = dn - (i0 + k);
      int jc = j < 0 ? 0 : (j > MM - 1 ? MM - 1 : j);
      dvn[k] = (float)Dr[(size_t)k * MM + jc];
    }
  }

  if (t == 255) out[b] = r1[3] * INV_SCALE;
}

// ---------------------------------------------------------------------------
extern "C" void kernel_launch(void* const* d_in, const int* in_sizes, int n_in,
                              void* d_out, int out_size, void* d_ws,
                              size_t ws_size, hipStream_t stream) {
  const float* x = (const float*)d_in[0];
  const float* y = (const float*)d_in[1];
  float* out = (float*)d_out;

  const size_t need_diag = (size_t)BATCH * DD * NN * sizeof(_Float16);  // ~134.5 MiB
  const size_t need_row  = (size_t)BATCH * NN * MM * sizeof(_Float16);  //   64  MiB
  dim3 g1(MM / 64, NN / 64, BATCH);

  if (ws_size >= need_diag) {
    _Float16* Dd = (_Float16*)d_ws;
    dist_kernel<1><<<g1, 256, 0, stream>>>(x, y, Dd);
    dtw_diag_kernel<<<BATCH, 256, 0, stream>>>(Dd, out);
  } else if (ws_size >= need_row) {
    _Float16* D = (_Float16*)d_ws;
    dist_kernel<0><<<g1, 256, 0, stream>>>(x, y, D);
    dtw_row_kernel<<<BATCH, 256, 0, stream>>>(D, out);
  }
  // else: workspace too small — fail visibly (output stays zero)
}

// Round 9
// 881.798 us; speedup vs baseline: 1.2841x; 1.2467x over previous
//
#include <hip/hip_runtime.h>
#include <hip/hip_bf16.h>

#define BATCH 32
#define NN 1024
#define MM 1024
#define KK 64
#define DD 2052                         // padded diag rows (used up to 2048)
#define SCALE 14.4269504088896f         // 1/(gamma*ln2), gamma = 0.1
#define INV_SCALE 0.0693147180559945f   // gamma*ln2
#define BIGU 1.44269504e11f             // 1e10 * SCALE

typedef _Float16 h4 __attribute__((ext_vector_type(4)));
typedef float f4 __attribute__((ext_vector_type(4)));

// Fused: LDS-write visibility + barrier in ONE asm (no compiler reordering
// around it, no vmcnt drain -> D prefetch loads stay in flight).
#define LDS_BARRIER() asm volatile("s_waitcnt lgkmcnt(0)\ns_barrier" ::: "memory")

// ---------------------------------------------------------------------------
// Kernel 1: pairwise sq-Euclidean distances, pre-scaled by 1/(gamma*ln2),
// stored f16. Unchanged from the verified R5/R7 version.
// ---------------------------------------------------------------------------
template <int DIAG>
__global__ __launch_bounds__(256) void dist_kernel(
    const float* __restrict__ x, const float* __restrict__ y,
    _Float16* __restrict__ D) {
  const int b  = blockIdx.z;
  const int ti = blockIdx.y;
  const int tj = blockIdx.x;
  const int t  = threadIdx.x;

  __shared__ float xs[64][68];
  __shared__ float ys[64][68];

  {
    const int lr = t >> 4;
    const int lc = (t & 15) * 4;
    const float* xp = x + (size_t)(b * NN + ti * 64) * KK;
    const float* yp = y + (size_t)(b * MM + tj * 64) * KK;
#pragma unroll
    for (int r = 0; r < 4; ++r) {
      const int row = lr + r * 16;
      f4 xv = *(const f4*)(xp + (size_t)row * KK + lc);
      f4 yv = *(const f4*)(yp + (size_t)row * KK + lc);
      xs[row][lc + 0] = xv[0]; xs[row][lc + 1] = xv[1];
      xs[row][lc + 2] = xv[2]; xs[row][lc + 3] = xv[3];
      ys[row][lc + 0] = yv[0]; ys[row][lc + 1] = yv[1];
      ys[row][lc + 2] = yv[2]; ys[row][lc + 3] = yv[3];
    }
  }
  __syncthreads();

  const int tx = (t & 15) * 4;
  const int ty = (t >> 4) * 4;

  float acc[4][4];
  float x2[4], y2[4];
#pragma unroll
  for (int a = 0; a < 4; ++a) {
    x2[a] = 0.f; y2[a] = 0.f;
#pragma unroll
    for (int c = 0; c < 4; ++c) acc[a][c] = 0.f;
  }

#pragma unroll 4
  for (int k = 0; k < KK; k += 4) {
    f4 xa[4], yb[4];
#pragma unroll
    for (int a = 0; a < 4; ++a) xa[a] = *(const f4*)&xs[ty + a][k];
#pragma unroll
    for (int c = 0; c < 4; ++c) yb[c] = *(const f4*)&ys[tx + c][k];
#pragma unroll
    for (int a = 0; a < 4; ++a) {
      x2[a] += xa[a][0] * xa[a][0] + xa[a][1] * xa[a][1] +
               xa[a][2] * xa[a][2] + xa[a][3] * xa[a][3];
      y2[a] += yb[a][0] * yb[a][0] + yb[a][1] * yb[a][1] +
               yb[a][2] * yb[a][2] + yb[a][3] * yb[a][3];
    }
#pragma unroll
    for (int a = 0; a < 4; ++a)
#pragma unroll
      for (int c = 0; c < 4; ++c)
        acc[a][c] += xa[a][0] * yb[c][0] + xa[a][1] * yb[c][1] +
                     xa[a][2] * yb[c][2] + xa[a][3] * yb[c][3];
  }

  if constexpr (DIAG) {
    __shared__ _Float16 dbuf[127][66];
#pragma unroll
    for (int a = 0; a < 4; ++a)
#pragma unroll
      for (int c = 0; c < 4; ++c) {
        const int li = ty + a, lj = tx + c;
        dbuf[li + lj][li] =
            (_Float16)((x2[a] + y2[c] - 2.0f * acc[a][c]) * SCALE);
      }
    __syncthreads();

    _Float16* Db = D + (size_t)b * DD * NN;
    const int wave = t >> 6, lane = t & 63;
    const int d0 = ti * 64 + tj * 64;
    const int c0 = ti * 64;
    for (int ld = wave; ld < 127; ld += 4) {
      const int lo = ld > 63 ? ld - 63 : 0;
      const int hi = ld < 63 ? ld : 63;
      const int li = lo + lane;
      if (li <= hi)
        Db[(size_t)(d0 + ld) * NN + c0 + li] = dbuf[ld][li];
    }
  } else {
    _Float16* Dp = D + (size_t)b * NN * MM + (size_t)(ti * 64 + ty) * MM +
                   (tj * 64 + tx);
#pragma unroll
    for (int a = 0; a < 4; ++a) {
      h4 v;
#pragma unroll
      for (int c = 0; c < 4; ++c)
        v[c] = (_Float16)((x2[a] + y2[c] - 2.0f * acc[a][c]) * SCALE);
      *(h4*)(Dp + (size_t)a * MM) = v;
    }
  }
}

// ---------------------------------------------------------------------------
// Kernel 2 (diag layout), halo version: 4 diagonals per barrier.
// Thread t owns rows i0..i0+3 (i0=4t); state w1/w2[8] covers rows i0-4..i0+3
// (w[j] = row i0-4+j). Per 4-block: one LDS exchange (neighbor's 4 rows at
// diags d0-1, d0-2), then 4 steps computing a shrinking staircase
// (j=c..7, 22 cells), all in registers with static indices.
// softmin via min3/med3/max3: s = 1 + 2^(mn-md) + 2^(mn-mx)  (2 exp, 1 log).
// D double-banked (7 h4 regs/bank), staged one block ahead; raw barrier
// keeps the loads in flight.
// ---------------------------------------------------------------------------
__global__ __launch_bounds__(256) void dtw_diag_kernel(
    const _Float16* __restrict__ Dd, float* __restrict__ out) {
  const int b  = blockIdx.x;
  const int t  = threadIdx.x;
  const int i0 = t * 4;
  const _Float16* Db = Dd + (size_t)b * DD * NN;

  __shared__ float lsx[2][256][8];   // [parity][thread][w1[4..7], w2[4..7]]

  float w1[8], w2[8];
#pragma unroll
  for (int j = 0; j < 8; ++j) { w1[j] = BIGU; w2[j] = BIGU; }
  if (t == 0) w1[4] = (float)Db[0];   // R[0,0] = D[0,0] (diag 0, row 0)

  // D banks: lo covers rows i0-4..i0-1, hi covers i0..i0+3, per diag c=0..3.
  h4 Al0, Al1, Al2, Ah0, Ah1, Ah2, Ah3;
  h4 Bl0, Bl1, Bl2, Bh0, Bh1, Bh2, Bh3;

#define STAGE(L0, L1, L2, H0, H1, H2, H3, D0S)                                \
  do {                                                                        \
    const long long _o = (long long)(D0S)*NN;                                 \
    L0 = *(const h4*)(Db + (size_t)(_o + i0 - 4));                            \
    L1 = *(const h4*)(Db + (size_t)(_o + NN + i0 - 4));                       \
    L2 = *(const h4*)(Db + (size_t)(_o + 2 * NN + i0 - 4));                   \
    H0 = *(const h4*)(Db + (size_t)(_o + i0));                                \
    H1 = *(const h4*)(Db + (size_t)(_o + NN + i0));                           \
    H2 = *(const h4*)(Db + (size_t)(_o + 2 * NN + i0));                       \
    H3 = *(const h4*)(Db + (size_t)(_o + 3 * NN + i0));                       \
  } while (0)

#define EXCHANGE(PAR)                                                         \
  do {                                                                        \
    f4 _s1, _s2;                                                              \
    _s1[0] = w1[4]; _s1[1] = w1[5]; _s1[2] = w1[6]; _s1[3] = w1[7];           \
    _s2[0] = w2[4]; _s2[1] = w2[5]; _s2[2] = w2[6]; _s2[3] = w2[7];           \
    *(f4*)&lsx[PAR][t][0] = _s1;                                              \
    *(f4*)&lsx[PAR][t][4] = _s2;                                              \
    LDS_BARRIER();                                                            \
    if (t > 0) {                                                              \
      f4 _h1 = *(const f4*)&lsx[PAR][t - 1][0];                               \
      f4 _h2 = *(const f4*)&lsx[PAR][t - 1][4];                               \
      w1[0] = _h1[0]; w1[1] = _h1[1]; w1[2] = _h1[2]; w1[3] = _h1[3];         \
      w2[0] = _h2[0]; w2[1] = _h2[1]; w2[2] = _h2[2]; w2[3] = _h2[3];         \
    }                                                                         \
  } while (0)

  // One DP cell, in-place (descending j keeps j-1 values old).
#define CELL(J, DV, DG)                                                       \
  do {                                                                        \
    const int _ri = i0 - 4 + (J);                                             \
    const bool _v =                                                           \
        ((unsigned)_ri < (unsigned)NN) && ((unsigned)((DG)-_ri) < (unsigned)MM); \
    const float _a = w2[(J)-1], _b = w1[(J)-1], _c = w1[(J)];                 \
    const float _mn = fminf(fminf(_a, _b), _c);                               \
    const float _md = __builtin_amdgcn_fmed3f(_a, _b, _c);                    \
    const float _mx = fmaxf(fmaxf(_a, _b), _c);                               \
    const float _s = 1.0f + __builtin_amdgcn_exp2f(_mn - _md) +               \
                     __builtin_amdgcn_exp2f(_mn - _mx);                       \
    w2[(J)] = w1[(J)];                                                        \
    w1[(J)] = _v ? (float)(DV) + _mn - __builtin_amdgcn_logf(_s) : BIGU;      \
  } while (0)

#define BLOCK4(PAR, L0, L1, L2, H0, H1, H2, H3, D0V)                          \
  do {                                                                        \
    EXCHANGE(PAR);                                                            \
    const int _d = (D0V);                                                     \
    /* c=1, diag _d,   j=7..1 */                                              \
    CELL(7, H0[3], _d); CELL(6, H0[2], _d); CELL(5, H0[1], _d);               \
    CELL(4, H0[0], _d); CELL(3, L0[3], _d); CELL(2, L0[2], _d);               \
    CELL(1, L0[1], _d);                                                       \
    /* c=2, diag _d+1, j=7..2 */                                              \
    CELL(7, H1[3], _d + 1); CELL(6, H1[2], _d + 1); CELL(5, H1[1], _d + 1);   \
    CELL(4, H1[0], _d + 1); CELL(3, L1[3], _d + 1); CELL(2, L1[2], _d + 1);   \
    /* c=3, diag _d+2, j=7..3 */                                              \
    CELL(7, H2[3], _d + 2); CELL(6, H2[2], _d + 2); CELL(5, H2[1], _d + 2);   \
    CELL(4, H2[0], _d + 2); CELL(3, L2[3], _d + 2);                           \
    /* c=4, diag _d+3, j=7..4 */                                              \
    CELL(7, H3[3], _d + 3); CELL(6, H3[2], _d + 3); CELL(5, H3[1], _d + 3);   \
    CELL(4, H3[0], _d + 3);                                                   \
  } while (0)

  STAGE(Al0, Al1, Al2, Ah0, Ah1, Ah2, Ah3, 1);   // block 0: diags 1..4
  STAGE(Bl0, Bl1, Bl2, Bh0, Bh1, Bh2, Bh3, 5);   // block 1: diags 5..8

  int d0 = 1;
  for (int n = 0; n < 255; ++n) {   // 255 pairs = blocks 0..509, diags 1..2040
    BLOCK4(0, Al0, Al1, Al2, Ah0, Ah1, Ah2, Ah3, d0);
    STAGE(Al0, Al1, Al2, Ah0, Ah1, Ah2, Ah3, d0 + 8);
    BLOCK4(1, Bl0, Bl1, Bl2, Bh0, Bh1, Bh2, Bh3, d0 + 4);
    STAGE(Bl0, Bl1, Bl2, Bh0, Bh1, Bh2, Bh3, d0 + 12);
    d0 += 8;
  }
  // d0 == 2041 here. Block 510 (parity 0, bank A): diags 2041..2044.
  BLOCK4(0, Al0, Al1, Al2, Ah0, Ah1, Ah2, Ah3, 2041);

  // Peel (parity 1, bank B staged with D0S=2045): diags 2045, 2046.
  EXCHANGE(1);
  CELL(7, Bh0[3], 2045); CELL(6, Bh0[2], 2045); CELL(5, Bh0[1], 2045);
  CELL(4, Bh0[0], 2045); CELL(3, Bl0[3], 2045); CELL(2, Bl0[2], 2045);
  CELL(1, Bl0[1], 2045);
  CELL(7, Bh1[3], 2046); CELL(6, Bh1[2], 2046); CELL(5, Bh1[1], 2046);
  CELL(4, Bh1[0], 2046); CELL(3, Bl1[3], 2046); CELL(2, Bl1[2], 2046);

  if (t == 255) out[b] = w1[7] * INV_SCALE;   // R[1023,1023], diag 2046

#undef STAGE
#undef EXCHANGE
#undef CELL
#undef BLOCK4
}

// ---------------------------------------------------------------------------
// Kernel 2 (row-major fallback): unchanged verified version.
// ---------------------------------------------------------------------------
__global__ __launch_bounds__(256) void dtw_row_kernel(
    const _Float16* __restrict__ D, float* __restrict__ out) {
  const int b  = blockIdx.x;
  const int t  = threadIdx.x;
  const int i0 = t * 4;
  const _Float16* Dr = D + (size_t)(b * NN + i0) * MM;

  __shared__ float lx[2][256];

  float r1[4], r2[4];
#pragma unroll
  for (int k = 0; k < 4; ++k) { r1[k] = BIGU; r2[k] = BIGU; }
  if (t == 0) r1[0] = (float)Dr[0];

  float dv[4], dvn[4];
#pragma unroll
  for (int k = 0; k < 4; ++k) {
    int j1 = 1 - (i0 + k);
    int jc1 = j1 < 0 ? 0 : (j1 > MM - 1 ? MM - 1 : j1);
    dv[k] = (float)Dr[(size_t)k * MM + jc1];
    int j2 = 2 - (i0 + k);
    int jc2 = j2 < 0 ? 0 : (j2 > MM - 1 ? MM - 1 : j2);
    dvn[k] = (float)Dr[(size_t)k * MM + jc2];
  }

  float nl1_prev = BIGU;

  for (int d = 1; d <= NN + MM - 2; ++d) {
    const int pp = d & 1;
    lx[pp][t] = r1[3];
    __syncthreads();
    const float nl1 = (t > 0) ? lx[pp][t - 1] : BIGU;
    const float nl2 = nl1_prev;

    float rn[4];
#pragma unroll
    for (int k = 0; k < 4; ++k) {
      const int j = d - (i0 + k);
      const float a  = k ? r2[k - 1] : nl2;
      const float bb = k ? r1[k - 1] : nl1;
      const float c  = r1[k];
      const float m  = fminf(fminf(a, bb), c);
      const float s  = exp2f(m - a) + exp2f(m - bb) + exp2f(m - c);
      const float sm = m - log2f(s);
      rn[k] = (j >= 0 && j < MM) ? dv[k] + sm : BIGU;
    }

    nl1_prev = nl1;
#pragma unroll
    for (int k = 0; k < 4; ++k) { r2[k] = r1[k]; r1[k] = rn[k]; dv[k] = dvn[k]; }

    const int dn = d + 2;
#pragma unroll
    for (int k = 0; k < 4; ++k) {
      int j = dn - (i0 + k);
      int jc = j < 0 ? 0 : (j > MM - 1 ? MM - 1 : j);
      dvn[k] = (float)Dr[(size_t)k * MM + jc];
    }
  }

  if (t == 255) out[b] = r1[3] * INV_SCALE;
}

// ---------------------------------------------------------------------------
extern "C" void kernel_launch(void* const* d_in, const int* in_sizes, int n_in,
                              void* d_out, int out_size, void* d_ws,
                              size_t ws_size, hipStream_t stream) {
  const float* x = (const float*)d_in[0];
  const float* y = (const float*)d_in[1];
  float* out = (float*)d_out;

  const size_t need_diag = (size_t)BATCH * DD * NN * sizeof(_Float16);  // ~134.5 MiB
  const size_t need_row  = (size_t)BATCH * NN * MM * sizeof(_Float16);  //   64  MiB
  dim3 g1(MM / 64, NN / 64, BATCH);

  if (ws_size >= need_diag) {
    _Float16* Dd = (_Float16*)d_ws;
    dist_kernel<1><<<g1, 256, 0, stream>>>(x, y, Dd);
    dtw_diag_kernel<<<BATCH, 256, 0, stream>>>(Dd, out);
  } else if (ws_size >= need_row) {
    _Float16* D = (_Float16*)d_ws;
    dist_kernel<0><<<g1, 256, 0, stream>>>(x, y, D);
    dtw_row_kernel<<<BATCH, 256, 0, stream>>>(D, out);
  }
  // else: workspace too small — fail visibly (output stays zero)
}